// Round 1
// baseline (447.928 us; speedup 1.0000x reference)
//
#include <hip/hip_runtime.h>

#define V_SIZE 50257
#define B_SIZE 256
#define S_LEN  15
#define H_DIM  512

typedef __attribute__((ext_vector_type(8))) short bf16x8;
typedef __attribute__((ext_vector_type(4))) float f32x4;

__device__ __forceinline__ unsigned short f2bf(float f) {
    unsigned int u = __float_as_uint(f);
    u += 0x7fffu + ((u >> 16) & 1u);   // RNE
    return (unsigned short)(u >> 16);
}

// ---------------------------------------------------------------------------
// K1: u[b,n] = sum_o h[b,o] * attn_W[o,n]   (fp32 vector; 67 MMAC total)
// grid (16 n-groups, 16 b-groups), block 256
// ---------------------------------------------------------------------------
__global__ __launch_bounds__(256) void u_kernel(
    const float* __restrict__ hidden, const float* __restrict__ attn_W,
    float* __restrict__ u)
{
    __shared__ float h_s[16][H_DIM];
    const int tid = threadIdx.x;
    const int b0 = blockIdx.y * 16, n0 = blockIdx.x * 32;
    const float4* hv = (const float4*)(hidden + (size_t)b0 * H_DIM);
    float4* hs4 = (float4*)&h_s[0][0];
    #pragma unroll
    for (int i = 0; i < 8; ++i) hs4[tid + i * 256] = hv[tid + i * 256];
    __syncthreads();
    const int n = n0 + (tid & 31);
    const int m = (tid >> 5) * 2;
    float a0 = 0.f, a1 = 0.f;
    #pragma unroll 8
    for (int o = 0; o < H_DIM; ++o) {
        float w = attn_W[(size_t)o * H_DIM + n];
        a0 += h_s[m][o] * w;
        a1 += h_s[m + 1][o] * w;
    }
    u[(size_t)(b0 + m) * H_DIM + n] = a0;
    u[(size_t)(b0 + m + 1) * H_DIM + n] = a1;
}

// ---------------------------------------------------------------------------
// K2: per-b attention: scores = enc·u, softmax, context; also gathers
// embedding and converts h, x=[emb,ctx] to bf16 for the GEMMs.
// grid (256), block 256
// ---------------------------------------------------------------------------
__global__ __launch_bounds__(256) void attn_kernel(
    const float* __restrict__ hidden, const float* __restrict__ enc,
    const float* __restrict__ u, const int* __restrict__ tokens,
    const float* __restrict__ emb, float* __restrict__ attnw_out,
    unsigned short* __restrict__ x_bf, unsigned short* __restrict__ h_bf)
{
    const int b = blockIdx.x, tid = threadIdx.x;
    __shared__ float u_s[H_DIM];
    __shared__ float sc_s[S_LEN];
    __shared__ float w_s[S_LEN];
    u_s[tid]       = u[(size_t)b * H_DIM + tid];
    u_s[tid + 256] = u[(size_t)b * H_DIM + tid + 256];
    h_bf[(size_t)b * H_DIM + tid]       = f2bf(hidden[(size_t)b * H_DIM + tid]);
    h_bf[(size_t)b * H_DIM + tid + 256] = f2bf(hidden[(size_t)b * H_DIM + tid + 256]);
    const int tok = tokens[b];
    x_bf[(size_t)b * 2 * H_DIM + tid]       = f2bf(emb[(size_t)tok * H_DIM + tid]);
    x_bf[(size_t)b * 2 * H_DIM + tid + 256] = f2bf(emb[(size_t)tok * H_DIM + tid + 256]);
    __syncthreads();
    const int wave = tid >> 6, lane = tid & 63;
    for (int s = wave; s < S_LEN; s += 4) {
        const float* e = enc + ((size_t)b * S_LEN + s) * H_DIM;
        float acc = 0.f;
        #pragma unroll
        for (int k = 0; k < H_DIM / 64; ++k) acc += e[lane + k * 64] * u_s[lane + k * 64];
        #pragma unroll
        for (int off = 32; off; off >>= 1) acc += __shfl_down(acc, off);
        if (lane == 0) sc_s[s] = acc;
    }
    __syncthreads();
    float mx = -1e30f;
    for (int s = 0; s < S_LEN; ++s) mx = fmaxf(mx, sc_s[s]);
    float sum = 0.f;
    for (int s = 0; s < S_LEN; ++s) sum += __expf(sc_s[s] - mx);
    const float inv = 1.f / sum;
    if (tid < S_LEN) {
        float w = __expf(sc_s[tid] - mx) * inv;
        w_s[tid] = w;
        attnw_out[b * S_LEN + tid] = w;
    }
    __syncthreads();
    #pragma unroll
    for (int hh = 0; hh < 2; ++hh) {
        int h = tid + hh * 256;
        float c = 0.f;
        #pragma unroll
        for (int s = 0; s < S_LEN; ++s)
            c += w_s[s] * enc[((size_t)b * S_LEN + s) * H_DIM + h];
        x_bf[(size_t)b * 2 * H_DIM + H_DIM + h] = f2bf(c);
    }
}

// ---------------------------------------------------------------------------
// Generic NT MFMA GEMM: C[M,N] = A[M,K](bf16) * B[N,K](f32->bf16)^T + bias
// 256 threads = 4 waves in 2x2; wave tile (BM/2)x(BN/2); 16x16x32 bf16 MFMA.
// blockIdx.z selects between two parameter sets (used to fuse gi/gh GEMMs).
// ---------------------------------------------------------------------------
struct GemmP {
    const unsigned short* A; const float* B; const float* bias; float* C;
    int N; int K;
};

template<int BM, int BN, int BK>
__global__ __launch_bounds__(256) void gemm_nt(GemmP p0, GemmP p1)
{
    GemmP p = (blockIdx.z == 0) ? p0 : p1;
    constexpr int LDA = BK + 8;              // +8 bf16 pad: keeps 16B align, 2-way max conflict
    __shared__ __align__(16) unsigned short As[BM][LDA];
    __shared__ __align__(16) unsigned short Bs[BN][LDA];
    const int tid = threadIdx.x;
    const int bn0 = blockIdx.x * BN;
    const int bm0 = blockIdx.y * BM;
    const int wave = tid >> 6, lane = tid & 63;
    const int wm = (wave >> 1) * (BM / 2);
    const int wn = (wave & 1) * (BN / 2);
    constexpr int MF = BM / 32, NF = BN / 32;
    const int n16 = lane & 15, quad = lane >> 4;

    f32x4 acc[MF][NF] = {};

    for (int k0 = 0; k0 < p.K; k0 += BK) {
        // stage A (already bf16): 8-elem (16B) per thread per iter
        #pragma unroll
        for (int it = 0; it < BM / 32; ++it) {
            int v = it * 256 + tid;
            int row = v >> 3, seg = v & 7;
            *(uint4*)&As[row][seg * 8] =
                *(const uint4*)(p.A + (size_t)(bm0 + row) * p.K + k0 + seg * 8);
        }
        // stage B (f32 -> bf16 cvt): 8 f32 per thread per iter
        #pragma unroll
        for (int it = 0; it < BN / 32; ++it) {
            int v = it * 256 + tid;
            int row = v >> 3, seg = v & 7;
            int gv = bn0 + row;
            float4 w0 = make_float4(0, 0, 0, 0), w1 = make_float4(0, 0, 0, 0);
            if (gv < p.N) {
                const float4* src = (const float4*)(p.B + (size_t)gv * p.K + k0 + seg * 8);
                w0 = src[0]; w1 = src[1];
            }
            uint4 pk;
            pk.x = (unsigned)f2bf(w0.x) | ((unsigned)f2bf(w0.y) << 16);
            pk.y = (unsigned)f2bf(w0.z) | ((unsigned)f2bf(w0.w) << 16);
            pk.z = (unsigned)f2bf(w1.x) | ((unsigned)f2bf(w1.y) << 16);
            pk.w = (unsigned)f2bf(w1.z) | ((unsigned)f2bf(w1.w) << 16);
            *(uint4*)&Bs[row][seg * 8] = pk;
        }
        __syncthreads();
        #pragma unroll
        for (int kk = 0; kk < BK; kk += 32) {
            bf16x8 af[MF], bfr[NF];
            #pragma unroll
            for (int i = 0; i < MF; ++i)
                af[i] = *(const bf16x8*)&As[wm + i * 16 + n16][kk + quad * 8];
            #pragma unroll
            for (int j = 0; j < NF; ++j)
                bfr[j] = *(const bf16x8*)&Bs[wn + j * 16 + n16][kk + quad * 8];
            #pragma unroll
            for (int i = 0; i < MF; ++i)
                #pragma unroll
                for (int j = 0; j < NF; ++j)
                    acc[i][j] = __builtin_amdgcn_mfma_f32_16x16x32_bf16(
                        af[i], bfr[j], acc[i][j], 0, 0, 0);
        }
        __syncthreads();
    }
    // epilogue: C/D layout col = lane&15, row = quad*4 + reg
    #pragma unroll
    for (int i = 0; i < MF; ++i) {
        const int r0 = bm0 + wm + i * 16 + quad * 4;
        #pragma unroll
        for (int j = 0; j < NF; ++j) {
            const int c = bn0 + wn + j * 16 + n16;
            if (c < p.N) {
                const float bv = p.bias[c];
                #pragma unroll
                for (int r = 0; r < 4; ++r)
                    p.C[(size_t)(r0 + r) * p.N + c] = acc[i][j][r] + bv;
            }
        }
    }
}

// ---------------------------------------------------------------------------
// K3c: GRU gate math (fp32), writes h_new (f32 to d_out) + bf16 copy for GEMM
// ---------------------------------------------------------------------------
__global__ __launch_bounds__(256) void gru_kernel(
    const float* __restrict__ gi, const float* __restrict__ gh,
    const float* __restrict__ hidden, float* __restrict__ hnew_out,
    unsigned short* __restrict__ hnew_bf)
{
    const int idx = blockIdx.x * 256 + threadIdx.x;   // < 131072
    const int b = idx >> 9, h = idx & 511;
    const float* gib = gi + (size_t)b * 3 * H_DIM;
    const float* ghb = gh + (size_t)b * 3 * H_DIM;
    float r = 1.f / (1.f + __expf(-(gib[h] + ghb[h])));
    float z = 1.f / (1.f + __expf(-(gib[H_DIM + h] + ghb[H_DIM + h])));
    float n = gib[2 * H_DIM + h] + r * ghb[2 * H_DIM + h];
    n = 1.f - 2.f / (1.f + __expf(2.f * n));          // tanh
    float hp = hidden[idx];
    float hn = (1.f - z) * n + z * hp;
    hnew_out[idx] = hn;
    hnew_bf[idx] = f2bf(hn);
}

// ---------------------------------------------------------------------------
// K5: per-row online log-softmax, in place on the logits in d_out
// grid (256), block 256
// ---------------------------------------------------------------------------
__global__ __launch_bounds__(256) void logsoftmax_kernel(float* __restrict__ logits)
{
    const int b = blockIdx.x, tid = threadIdx.x;
    float* row = logits + (size_t)b * V_SIZE;
    float m = -1e30f, s = 0.f;
    for (int c = tid; c < V_SIZE; c += 256) {
        float x = row[c];
        float nm = fmaxf(m, x);
        s = s * __expf(m - nm) + __expf(x - nm);
        m = nm;
    }
    const int lane = tid & 63, wave = tid >> 6;
    #pragma unroll
    for (int off = 32; off; off >>= 1) {
        float m2 = __shfl_down(m, off), s2 = __shfl_down(s, off);
        float nm = fmaxf(m, m2);
        s = s * __expf(m - nm) + s2 * __expf(m2 - nm);
        m = nm;
    }
    __shared__ float msh[4], ssh[4], lse_sh;
    if (lane == 0) { msh[wave] = m; ssh[wave] = s; }
    __syncthreads();
    if (tid == 0) {
        float M = msh[0], S = ssh[0];
        for (int w = 1; w < 4; ++w) {
            float nm = fmaxf(M, msh[w]);
            S = S * __expf(M - nm) + ssh[w] * __expf(msh[w] - nm);
            M = nm;
        }
        lse_sh = M + logf(S);
    }
    __syncthreads();
    const float lse = lse_sh;
    for (int c = tid; c < V_SIZE; c += 256) row[c] -= lse;
}

// ---------------------------------------------------------------------------
// workspace layout (bytes)
// ---------------------------------------------------------------------------
constexpr size_t OFF_U      = 0;         // 256*512*4  = 524288
constexpr size_t OFF_XBF    = 524288;    // 256*1024*2 = 524288
constexpr size_t OFF_HBF    = 1048576;   // 256*512*2  = 262144
constexpr size_t OFF_HNEWBF = 1310720;   // 262144
constexpr size_t OFF_GI     = 1572864;   // 256*1536*4 = 1572864
constexpr size_t OFF_GH     = 3145728;   // 1572864    (end: 4718592)

extern "C" void kernel_launch(void* const* d_in, const int* in_sizes, int n_in,
                              void* d_out, int out_size, void* d_ws, size_t ws_size,
                              hipStream_t stream) {
    const int*   tokens = (const int*)d_in[0];
    const float* hidden = (const float*)d_in[1];
    const float* enc    = (const float*)d_in[2];
    const float* emb    = (const float*)d_in[3];
    const float* attn_W = (const float*)d_in[4];
    // d_in[5] = attn_b: constant across s -> cancels in softmax; unused
    const float* W_ih   = (const float*)d_in[6];
    const float* W_hh   = (const float*)d_in[7];
    const float* b_ih   = (const float*)d_in[8];
    const float* b_hh   = (const float*)d_in[9];
    const float* out_W  = (const float*)d_in[10];
    const float* out_b  = (const float*)d_in[11];

    float* out = (float*)d_out;
    float* logp      = out;                                   // [256][50257]
    float* hnew_out  = out + (size_t)B_SIZE * V_SIZE;         // [256][512]
    float* attnw_out = hnew_out + (size_t)B_SIZE * H_DIM;     // [256][15]

    char* ws = (char*)d_ws;
    float*          u_ws    = (float*)(ws + OFF_U);
    unsigned short* x_bf    = (unsigned short*)(ws + OFF_XBF);
    unsigned short* h_bf    = (unsigned short*)(ws + OFF_HBF);
    unsigned short* hnew_bf = (unsigned short*)(ws + OFF_HNEWBF);
    float*          gi_ws   = (float*)(ws + OFF_GI);
    float*          gh_ws   = (float*)(ws + OFF_GH);

    u_kernel<<<dim3(16, 16), 256, 0, stream>>>(hidden, attn_W, u_ws);
    attn_kernel<<<dim3(256), 256, 0, stream>>>(hidden, enc, u_ws, tokens, emb,
                                               attnw_out, x_bf, h_bf);
    GemmP gi_p { x_bf, W_ih, b_ih, gi_ws, 3 * H_DIM, 2 * H_DIM };
    GemmP gh_p { h_bf, W_hh, b_hh, gh_ws, 3 * H_DIM, H_DIM };
    gemm_nt<64, 64, 64><<<dim3(24, 4, 2), 256, 0, stream>>>(gi_p, gh_p);
    gru_kernel<<<dim3(512), 256, 0, stream>>>(gi_ws, gh_ws, hidden, hnew_out, hnew_bf);
    GemmP lg { hnew_bf, out_W, out_b, logp, V_SIZE, H_DIM };
    gemm_nt<256, 128, 64><<<dim3((V_SIZE + 127) / 128, 1, 1), 256, 0, stream>>>(lg, lg);
    logsoftmax_kernel<<<dim3(256), 256, 0, stream>>>(logp);
}

// Round 2
// 375.420 us; speedup vs baseline: 1.1931x; 1.1931x over previous
//
#include <hip/hip_runtime.h>

#define V_SIZE 50257
#define B_SIZE 256
#define S_LEN  15
#define H_DIM  512

typedef __attribute__((ext_vector_type(8))) short bf16x8;
typedef __attribute__((ext_vector_type(4))) float f32x4;

__device__ __forceinline__ unsigned short f2bf(float f) {
    unsigned int u = __float_as_uint(f);
    u += 0x7fffu + ((u >> 16) & 1u);   // RNE
    return (unsigned short)(u >> 16);
}

// ---------------------------------------------------------------------------
// K1: u[b,n] = sum_o h[b,o] * attn_W[o,n]   (fp32 vector; 67 MMAC total)
// grid (16 n-groups, 16 b-groups), block 256
// ---------------------------------------------------------------------------
__global__ __launch_bounds__(256) void u_kernel(
    const float* __restrict__ hidden, const float* __restrict__ attn_W,
    float* __restrict__ u)
{
    __shared__ float h_s[16][H_DIM];
    const int tid = threadIdx.x;
    const int b0 = blockIdx.y * 16, n0 = blockIdx.x * 32;
    const float4* hv = (const float4*)(hidden + (size_t)b0 * H_DIM);
    float4* hs4 = (float4*)&h_s[0][0];
    #pragma unroll
    for (int i = 0; i < 8; ++i) hs4[tid + i * 256] = hv[tid + i * 256];
    __syncthreads();
    const int n = n0 + (tid & 31);
    const int m = (tid >> 5) * 2;
    float a0 = 0.f, a1 = 0.f;
    #pragma unroll 8
    for (int o = 0; o < H_DIM; ++o) {
        float w = attn_W[(size_t)o * H_DIM + n];
        a0 += h_s[m][o] * w;
        a1 += h_s[m + 1][o] * w;
    }
    u[(size_t)(b0 + m) * H_DIM + n] = a0;
    u[(size_t)(b0 + m + 1) * H_DIM + n] = a1;
}

// ---------------------------------------------------------------------------
// K2: per-b attention: scores = enc·u, softmax, context; also gathers
// embedding and converts h, x=[emb,ctx] to bf16 for the GEMMs.
// grid (256), block 256
// ---------------------------------------------------------------------------
__global__ __launch_bounds__(256) void attn_kernel(
    const float* __restrict__ hidden, const float* __restrict__ enc,
    const float* __restrict__ u, const int* __restrict__ tokens,
    const float* __restrict__ emb, float* __restrict__ attnw_out,
    unsigned short* __restrict__ x_bf, unsigned short* __restrict__ h_bf)
{
    const int b = blockIdx.x, tid = threadIdx.x;
    __shared__ float u_s[H_DIM];
    __shared__ float sc_s[S_LEN];
    __shared__ float w_s[S_LEN];
    u_s[tid]       = u[(size_t)b * H_DIM + tid];
    u_s[tid + 256] = u[(size_t)b * H_DIM + tid + 256];
    h_bf[(size_t)b * H_DIM + tid]       = f2bf(hidden[(size_t)b * H_DIM + tid]);
    h_bf[(size_t)b * H_DIM + tid + 256] = f2bf(hidden[(size_t)b * H_DIM + tid + 256]);
    const int tok = tokens[b];
    x_bf[(size_t)b * 2 * H_DIM + tid]       = f2bf(emb[(size_t)tok * H_DIM + tid]);
    x_bf[(size_t)b * 2 * H_DIM + tid + 256] = f2bf(emb[(size_t)tok * H_DIM + tid + 256]);
    __syncthreads();
    const int wave = tid >> 6, lane = tid & 63;
    for (int s = wave; s < S_LEN; s += 4) {
        const float* e = enc + ((size_t)b * S_LEN + s) * H_DIM;
        float acc = 0.f;
        #pragma unroll
        for (int k = 0; k < H_DIM / 64; ++k) acc += e[lane + k * 64] * u_s[lane + k * 64];
        #pragma unroll
        for (int off = 32; off; off >>= 1) acc += __shfl_down(acc, off);
        if (lane == 0) sc_s[s] = acc;
    }
    __syncthreads();
    float mx = -1e30f;
    for (int s = 0; s < S_LEN; ++s) mx = fmaxf(mx, sc_s[s]);
    float sum = 0.f;
    for (int s = 0; s < S_LEN; ++s) sum += __expf(sc_s[s] - mx);
    const float inv = 1.f / sum;
    if (tid < S_LEN) {
        float w = __expf(sc_s[tid] - mx) * inv;
        w_s[tid] = w;
        attnw_out[b * S_LEN + tid] = w;
    }
    __syncthreads();
    #pragma unroll
    for (int hh = 0; hh < 2; ++hh) {
        int h = tid + hh * 256;
        float c = 0.f;
        #pragma unroll
        for (int s = 0; s < S_LEN; ++s)
            c += w_s[s] * enc[((size_t)b * S_LEN + s) * H_DIM + h];
        x_bf[(size_t)b * 2 * H_DIM + H_DIM + h] = f2bf(c);
    }
}

// ---------------------------------------------------------------------------
// Generic NT MFMA GEMM: C[M,N] = A[M,K](bf16) * B[N,K](f32->bf16)^T + bias
// 256 threads = 4 waves in WR x WC; wave tile (BM/WR)x(BN/WC); 16x16x32 MFMA.
// blockIdx.z selects between two parameter sets (used to fuse gi/gh GEMMs).
// ---------------------------------------------------------------------------
struct GemmP {
    const unsigned short* A; const float* B; const float* bias; float* C;
    int N; int K;
};

template<int BM, int BN, int BK, int WR, int WC>
__global__ __launch_bounds__(256) void gemm_nt(GemmP p0, GemmP p1)
{
    GemmP p = (blockIdx.z == 0) ? p0 : p1;
    constexpr int LDA = BK + 8;              // +8 bf16 pad: keeps 16B align
    __shared__ __align__(16) unsigned short As[BM][LDA];
    __shared__ __align__(16) unsigned short Bs[BN][LDA];
    const int tid = threadIdx.x;
    const int bn0 = blockIdx.x * BN;
    const int bm0 = blockIdx.y * BM;
    const int wave = tid >> 6, lane = tid & 63;
    const int wm = (wave / WC) * (BM / WR);
    const int wn = (wave % WC) * (BN / WC);
    constexpr int MF = BM / WR / 16, NF = BN / WC / 16;
    const int n16 = lane & 15, quad = lane >> 4;

    f32x4 acc[MF][NF] = {};

    for (int k0 = 0; k0 < p.K; k0 += BK) {
        // stage A (already bf16): 8-elem (16B) per thread per iter
        #pragma unroll
        for (int it = 0; it < BM / 32; ++it) {
            int v = it * 256 + tid;
            int row = v >> 3, seg = v & 7;
            *(uint4*)&As[row][seg * 8] =
                *(const uint4*)(p.A + (size_t)(bm0 + row) * p.K + k0 + seg * 8);
        }
        // stage B (f32 -> bf16 cvt): 8 f32 per thread per iter
        #pragma unroll
        for (int it = 0; it < BN / 32; ++it) {
            int v = it * 256 + tid;
            int row = v >> 3, seg = v & 7;
            int gv = bn0 + row;
            float4 w0 = make_float4(0, 0, 0, 0), w1 = make_float4(0, 0, 0, 0);
            if (gv < p.N) {
                const float4* src = (const float4*)(p.B + (size_t)gv * p.K + k0 + seg * 8);
                w0 = src[0]; w1 = src[1];
            }
            uint4 pk;
            pk.x = (unsigned)f2bf(w0.x) | ((unsigned)f2bf(w0.y) << 16);
            pk.y = (unsigned)f2bf(w0.z) | ((unsigned)f2bf(w0.w) << 16);
            pk.z = (unsigned)f2bf(w1.x) | ((unsigned)f2bf(w1.y) << 16);
            pk.w = (unsigned)f2bf(w1.z) | ((unsigned)f2bf(w1.w) << 16);
            *(uint4*)&Bs[row][seg * 8] = pk;
        }
        __syncthreads();
        #pragma unroll
        for (int kk = 0; kk < BK; kk += 32) {
            bf16x8 af[MF], bfr[NF];
            #pragma unroll
            for (int i = 0; i < MF; ++i)
                af[i] = *(const bf16x8*)&As[wm + i * 16 + n16][kk + quad * 8];
            #pragma unroll
            for (int j = 0; j < NF; ++j)
                bfr[j] = *(const bf16x8*)&Bs[wn + j * 16 + n16][kk + quad * 8];
            #pragma unroll
            for (int i = 0; i < MF; ++i)
                #pragma unroll
                for (int j = 0; j < NF; ++j)
                    acc[i][j] = __builtin_amdgcn_mfma_f32_16x16x32_bf16(
                        af[i], bfr[j], acc[i][j], 0, 0, 0);
        }
        __syncthreads();
    }
    // epilogue: C/D layout col = lane&15, row = quad*4 + reg
    #pragma unroll
    for (int i = 0; i < MF; ++i) {
        const int r0 = bm0 + wm + i * 16 + quad * 4;
        #pragma unroll
        for (int j = 0; j < NF; ++j) {
            const int c = bn0 + wn + j * 16 + n16;
            if (c < p.N) {
                const float bv = p.bias[c];
                #pragma unroll
                for (int r = 0; r < 4; ++r)
                    p.C[(size_t)(r0 + r) * p.N + c] = acc[i][j][r] + bv;
            }
        }
    }
}

// ---------------------------------------------------------------------------
// K3c: GRU gate math (fp32), writes h_new (f32 to d_out) + bf16 copy for GEMM
// ---------------------------------------------------------------------------
__global__ __launch_bounds__(256) void gru_kernel(
    const float* __restrict__ gi, const float* __restrict__ gh,
    const float* __restrict__ hidden, float* __restrict__ hnew_out,
    unsigned short* __restrict__ hnew_bf)
{
    const int idx = blockIdx.x * 256 + threadIdx.x;   // < 131072
    const int b = idx >> 9, h = idx & 511;
    const float* gib = gi + (size_t)b * 3 * H_DIM;
    const float* ghb = gh + (size_t)b * 3 * H_DIM;
    float r = 1.f / (1.f + __expf(-(gib[h] + ghb[h])));
    float z = 1.f / (1.f + __expf(-(gib[H_DIM + h] + ghb[H_DIM + h])));
    float n = gib[2 * H_DIM + h] + r * ghb[2 * H_DIM + h];
    n = 1.f - 2.f / (1.f + __expf(2.f * n));          // tanh
    float hp = hidden[idx];
    float hn = (1.f - z) * n + z * hp;
    hnew_out[idx] = hn;
    hnew_bf[idx] = f2bf(hn);
}

// ---------------------------------------------------------------------------
// K5: per-row online log-softmax, in place on the logits in d_out
// grid (256), block 1024 (16 waves -> better latency hiding on 154 MB pass)
// ---------------------------------------------------------------------------
__global__ __launch_bounds__(1024) void logsoftmax_kernel(float* __restrict__ logits)
{
    const int b = blockIdx.x, tid = threadIdx.x;
    float* row = logits + (size_t)b * V_SIZE;
    float m = -1e30f, s = 0.f;
    for (int c = tid; c < V_SIZE; c += 1024) {
        float x = row[c];
        float nm = fmaxf(m, x);
        s = s * __expf(m - nm) + __expf(x - nm);
        m = nm;
    }
    const int lane = tid & 63, wave = tid >> 6;
    #pragma unroll
    for (int off = 32; off; off >>= 1) {
        float m2 = __shfl_down(m, off), s2 = __shfl_down(s, off);
        float nm = fmaxf(m, m2);
        s = s * __expf(m - nm) + s2 * __expf(m2 - nm);
        m = nm;
    }
    __shared__ float msh[16], ssh[16], lse_sh;
    if (lane == 0) { msh[wave] = m; ssh[wave] = s; }
    __syncthreads();
    if (tid == 0) {
        float M = msh[0], S = ssh[0];
        for (int w = 1; w < 16; ++w) {
            float nm = fmaxf(M, msh[w]);
            S = S * __expf(M - nm) + ssh[w] * __expf(msh[w] - nm);
            M = nm;
        }
        lse_sh = M + logf(S);
    }
    __syncthreads();
    const float lse = lse_sh;
    for (int c = tid; c < V_SIZE; c += 1024) row[c] -= lse;
}

// ---------------------------------------------------------------------------
// workspace layout (bytes)
// ---------------------------------------------------------------------------
constexpr size_t OFF_U      = 0;         // 256*512*4  = 524288
constexpr size_t OFF_XBF    = 524288;    // 256*1024*2 = 524288
constexpr size_t OFF_HBF    = 1048576;   // 256*512*2  = 262144
constexpr size_t OFF_HNEWBF = 1310720;   // 262144
constexpr size_t OFF_GI     = 1572864;   // 256*1536*4 = 1572864
constexpr size_t OFF_GH     = 3145728;   // 1572864    (end: 4718592)

extern "C" void kernel_launch(void* const* d_in, const int* in_sizes, int n_in,
                              void* d_out, int out_size, void* d_ws, size_t ws_size,
                              hipStream_t stream) {
    const int*   tokens = (const int*)d_in[0];
    const float* hidden = (const float*)d_in[1];
    const float* enc    = (const float*)d_in[2];
    const float* emb    = (const float*)d_in[3];
    const float* attn_W = (const float*)d_in[4];
    // d_in[5] = attn_b: constant across s -> cancels in softmax; unused
    const float* W_ih   = (const float*)d_in[6];
    const float* W_hh   = (const float*)d_in[7];
    const float* b_ih   = (const float*)d_in[8];
    const float* b_hh   = (const float*)d_in[9];
    const float* out_W  = (const float*)d_in[10];
    const float* out_b  = (const float*)d_in[11];

    float* out = (float*)d_out;
    float* logp      = out;                                   // [256][50257]
    float* hnew_out  = out + (size_t)B_SIZE * V_SIZE;         // [256][512]
    float* attnw_out = hnew_out + (size_t)B_SIZE * H_DIM;     // [256][15]

    char* ws = (char*)d_ws;
    float*          u_ws    = (float*)(ws + OFF_U);
    unsigned short* x_bf    = (unsigned short*)(ws + OFF_XBF);
    unsigned short* h_bf    = (unsigned short*)(ws + OFF_HBF);
    unsigned short* hnew_bf = (unsigned short*)(ws + OFF_HNEWBF);
    float*          gi_ws   = (float*)(ws + OFF_GI);
    float*          gh_ws   = (float*)(ws + OFF_GH);

    u_kernel<<<dim3(16, 16), 256, 0, stream>>>(hidden, attn_W, u_ws);
    attn_kernel<<<dim3(256), 256, 0, stream>>>(hidden, enc, u_ws, tokens, emb,
                                               attnw_out, x_bf, h_bf);
    GemmP gi_p { x_bf, W_ih, b_ih, gi_ws, 3 * H_DIM, 2 * H_DIM };
    GemmP gh_p { h_bf, W_hh, b_hh, gh_ws, 3 * H_DIM, H_DIM };
    gemm_nt<64, 64, 64, 2, 2><<<dim3(24, 4, 2), 256, 0, stream>>>(gi_p, gh_p);
    gru_kernel<<<dim3(512), 256, 0, stream>>>(gi_ws, gh_ws, hidden, hnew_out, hnew_bf);
    GemmP lg { hnew_bf, out_W, out_b, logp, V_SIZE, H_DIM };
    // BM=256 (full M): out_W streamed exactly once; 786 blocks ~ 3/CU
    gemm_nt<256, 64, 64, 4, 1><<<dim3((V_SIZE + 63) / 64, 1, 1), 256, 0, stream>>>(lg, lg);
    logsoftmax_kernel<<<dim3(256), 1024, 0, stream>>>(logp);
}